// Round 1
// 2825.724 us; speedup vs baseline: 1.0053x; 1.0053x over previous
//
#include <hip/hip_runtime.h>
#include <hip/hip_bf16.h>
#include <cstdint>
#include <cstddef>

typedef __attribute__((ext_vector_type(8))) short bf16x8;
typedef __attribute__((ext_vector_type(4))) float f32x4;

#define DEV __device__ __forceinline__

DEV unsigned short f2bf(float f) {
  unsigned int u = __float_as_uint(f);
  return (unsigned short)((u + 0x7fffu + ((u >> 16) & 1u)) >> 16);
}

DEV void gl_lds16(const unsigned short* g, unsigned short* l) {
  __builtin_amdgcn_global_load_lds(
      (__attribute__((address_space(1))) const void*)g,
      (__attribute__((address_space(3))) void*)l, 16, 0, 0);
}

// ---- states fp32 -> bf16 (exact grid: 4096 blocks x 256 thr x 1 float4) ----
__global__ __launch_bounds__(256) void cvt_kernel(const float* __restrict__ src,
                                                  unsigned short* __restrict__ dst) {
  size_t i = (size_t)blockIdx.x * 256 + threadIdx.x;
  float4 v = ((const float4*)src)[i];
  ushort4 o;
  o.x = f2bf(v.x); o.y = f2bf(v.y); o.z = f2bf(v.z); o.w = f2bf(v.w);
  ((ushort4*)dst)[i] = o;
}

// ---- zero an fp32 buffer (grid 4096 x 256 x float4 = 4M floats) ----
__global__ __launch_bounds__(256) void zero_kernel(float* __restrict__ p) {
  size_t i = (size_t)blockIdx.x * 256 + threadIdx.x;
  ((float4*)p)[i] = make_float4(0.f, 0.f, 0.f, 0.f);
}

// ---- S fp32 -> bf16 state, and re-zero S for the next node ----
__global__ __launch_bounds__(256) void cvtzero_kernel(float* __restrict__ s,
                                                      unsigned short* __restrict__ dst) {
  size_t i = (size_t)blockIdx.x * 256 + threadIdx.x;
  float4 v = ((float4*)s)[i];
  ushort4 o;
  o.x = f2bf(v.x); o.y = f2bf(v.y); o.z = f2bf(v.z); o.w = f2bf(v.w);
  ((ushort4*)dst)[i] = o;
  ((float4*)s)[i] = make_float4(0.f, 0.f, 0.f, 0.f);
}

// ---- weights: src [nmat][K][1024] f32 -> dst bf16, transposed, K-half-split:
// element (n, k) stored at mat*1024*K + (k>>10)*1024*1024 + n*1024 + (k&1023)
// => every 1024-K segment is a [1024 n][1024 k] matrix with uniform stride 1024.
__global__ __launch_bounds__(256) void transpose_kernel(const float* __restrict__ src,
                                                        unsigned short* __restrict__ dst,
                                                        int K) {
  __shared__ float tile[64][68];
  const int t = threadIdx.x;
  const int tpm = (K >> 6) * 16;  // 64x64 tiles per matrix
  const int mat = blockIdx.x / tpm;
  const int r = blockIdx.x % tpm;
  const int tk = r >> 4;
  const int tn = r & 15;
  const size_t sbase = (size_t)mat * K * 1024 + (size_t)tk * 64 * 1024 + (size_t)tn * 64;
#pragma unroll
  for (int p = 0; p < 4; ++p) {
    int row = p * 16 + (t >> 4);
    int c4 = (t & 15) * 4;
    float4 v = *(const float4*)&src[sbase + (size_t)row * 1024 + c4];
    *(float4*)&tile[row][c4] = v;
  }
  __syncthreads();
  const int kbase = tk * 64;
  const size_t dbase = (size_t)mat * 1024 * K + (size_t)(kbase >> 10) * 1024 * 1024 +
                       (size_t)tn * 64 * 1024 + (size_t)(kbase & 1023);
#pragma unroll
  for (int p = 0; p < 4; ++p) {
    int n = p * 16 + (t >> 4);
    int k4 = (t & 15) * 4;
    ushort4 o;
    o.x = f2bf(tile[k4 + 0][n]);
    o.y = f2bf(tile[k4 + 1][n]);
    o.z = f2bf(tile[k4 + 2][n]);
    o.w = f2bf(tile[k4 + 3][n]);
    *(ushort4*)&dst[dbase + (size_t)n * 1024 + k4] = o;
  }
}

// A segment is a K=1024 slice of one edge's GEMM. Concat(2D-input) edges are two
// segments sharing the accumulator; epilogue (act + genotype-weighted sum) fires
// only on the segment with last=1.
struct SegCfg {
  const unsigned short* x;  // A rows (bf16, stride 1024)
  const unsigned short* w;  // W base for op 0 (bf16, [1024 n][1024 k], stride 1024)
  size_t wops;              // per-op stride (inlen*1024)
  int l;                    // layer index into genotype/bs
  int last;                 // 1 => run epilogue after this segment
};
struct NodeArgs {
  SegCfg s[7];
  int nseg;
};

// Op-split GEMM: grid (8 bn, 32 bm, 5 op). BM=BN=128, BK=32, 4 waves of 64x64.
// Double-buffered LDS pipeline: stage step s+1 while computing step s; one
// barrier per K-step. LDS layout is the conflict-free 8-row block layout:
//   byte(row, chunk16B) = (row>>3)*512 + chunk*128 + (row&7)*16
// achieved by permuting the per-lane *global source* address (LDS dest stays
// linear, as global_load_lds requires).
__global__ __launch_bounds__(256, 2) void node_gemm(NodeArgs na,
                                                    const float* __restrict__ genotype,
                                                    const float* __restrict__ bs,
                                                    float* __restrict__ sout) {
  __shared__ unsigned short lds[16384];  // A0|B0|A1|B1, 4096 shorts (8KB) each

  const int t = threadIdx.x;
  const int lane = t & 63;
  const int w = t >> 6;
  const int wm = (w & 1) * 64;
  const int wn = (w >> 1) * 64;
  const int bn = blockIdx.x * 128;
  const int bm = blockIdx.y * 128;
  const int kop = blockIdx.z;  // which of the 5 candidate ops (uniform per block)
  const int l15 = lane & 15;
  const int l16 = lane >> 4;

  // staging decode: thread t's linear LDS slot (t*16B) corresponds to
  // row = (t>>5)*8 + (t&7), chunk = (t>>3)&3 in the block layout.
  const int srow = ((t >> 5) << 3) | (t & 7);
  const int schunk = (t >> 3) & 3;
  const size_t aoffg = (size_t)(bm + srow) * 1024 + schunk * 8;  // A source offset (shorts)
  const size_t boffg = (size_t)(bn + srow) * 1024 + schunk * 8;  // B source offset

  unsigned short* dA0 = lds + t * 8;
  unsigned short* dB0 = lds + 4096 + t * 8;
  unsigned short* dA1 = lds + 8192 + t * 8;
  unsigned short* dB1 = lds + 12288 + t * 8;

  // per-lane fragment read offsets (shorts) in the block layout; constant over K
  int aof[4], bof[4];
#pragma unroll
  for (int mi = 0; mi < 4; ++mi) {
    int r = wm + mi * 16 + l15;
    aof[mi] = (r >> 3) * 256 + l16 * 64 + (r & 7) * 8;
  }
#pragma unroll
  for (int ni = 0; ni < 4; ++ni) {
    int r = wn + ni * 16 + l15;
    bof[ni] = (r >> 3) * 256 + l16 * 64 + (r & 7) * 8;
  }

  f32x4 sacc[4][4];
  f32x4 hacc[4][4];
#pragma unroll
  for (int mi = 0; mi < 4; ++mi)
#pragma unroll
    for (int ni = 0; ni < 4; ++ni) {
      sacc[mi][ni] = (f32x4){0.f, 0.f, 0.f, 0.f};
      hacc[mi][ni] = (f32x4){0.f, 0.f, 0.f, 0.f};
    }

  auto stage = [&](const unsigned short* pa, const unsigned short* pb,
                   unsigned short* da, unsigned short* db) {
    gl_lds16(pa, da);
    gl_lds16(pa + 64 * 1024, da + 2048);
    gl_lds16(pb, db);
    gl_lds16(pb + 64 * 1024, db + 2048);
  };

  auto compute = [&](const unsigned short* Ab, const unsigned short* Bb) {
    bf16x8 af[4], bfr[4];
#pragma unroll
    for (int mi = 0; mi < 4; ++mi) af[mi] = *(const bf16x8*)&Ab[aof[mi]];
#pragma unroll
    for (int ni = 0; ni < 4; ++ni) bfr[ni] = *(const bf16x8*)&Bb[bof[ni]];
#pragma unroll
    for (int mi = 0; mi < 4; ++mi)
#pragma unroll
      for (int ni = 0; ni < 4; ++ni)
        hacc[mi][ni] = __builtin_amdgcn_mfma_f32_16x16x32_bf16(af[mi], bfr[ni],
                                                               hacc[mi][ni], 0, 0, 0);
  };

  auto epilogue = [&](int l) {
    const float wlk = genotype[l * 5 + kop];
    const float* bv = bs + ((size_t)l * 5 + kop) * 1024;
#pragma unroll
    for (int ni = 0; ni < 4; ++ni) {
      const float bias = bv[bn + wn + ni * 16 + l15];  // C-frag: col = lane&15
#pragma unroll
      for (int mi = 0; mi < 4; ++mi)
#pragma unroll
        for (int i = 0; i < 4; ++i) {
          float h = hacc[mi][ni][i] + bias;
          float a;
          if (kop == 0) a = h;
          else if (kop == 1) a = fmaxf(h, 0.f);
          else if (kop == 2) a = 1.f - 2.f / (__expf(2.f * h) + 1.f);  // tanh, NaN-free
          else if (kop == 3) a = 1.f / (1.f + __expf(-h));             // sigmoid
          else a = (h > 0.f) ? h : 0.2f * h;                           // leaky_relu(0.2)
          sacc[mi][ni][i] += wlk * a;
          hacc[mi][ni][i] = 0.f;
        }
    }
  };

  // prologue: stage segment 0, step 0 into buffer 0
  const unsigned short* pa = na.s[0].x + aoffg;
  const unsigned short* pb = na.s[0].w + (size_t)kop * na.s[0].wops + boffg;
  int cl = na.s[0].l, clast = na.s[0].last;
  stage(pa, pb, dA0, dB0);
  __syncthreads();

  for (int e = 0; e < na.nseg; ++e) {
    // steps 0..29 (15 double-steps): fully regular
#pragma unroll 1
    for (int kt2 = 0; kt2 < 15; ++kt2) {
      // even step: compute buf0, prefetch step 2*kt2+1 -> buf1
      stage(pa + (2 * kt2 + 1) * 32, pb + (2 * kt2 + 1) * 32, dA1, dB1);
      compute(lds, lds + 4096);
      __syncthreads();
      // odd step: compute buf1, prefetch step 2*kt2+2 -> buf0
      stage(pa + (2 * kt2 + 2) * 32, pb + (2 * kt2 + 2) * 32, dA0, dB0);
      compute(lds + 8192, lds + 12288);
      __syncthreads();
    }
    // step 30: compute buf0, prefetch step 31 -> buf1
    stage(pa + 31 * 32, pb + 31 * 32, dA1, dB1);
    compute(lds, lds + 4096);
    __syncthreads();
    // step 31: prefetch next segment's step 0 -> buf0, compute buf1, epilogue
    if (e + 1 < na.nseg) {
      pa = na.s[e + 1].x + aoffg;
      pb = na.s[e + 1].w + (size_t)kop * na.s[e + 1].wops + boffg;
      stage(pa, pb, dA0, dB0);
    }
    compute(lds + 8192, lds + 12288);
    if (clast) epilogue(cl);
    if (e + 1 < na.nseg) {
      cl = na.s[e + 1].l;
      clast = na.s[e + 1].last;
    }
    __syncthreads();
  }

  // one atomic pass per block: 5 op-blocks reduce into sout
#pragma unroll
  for (int mi = 0; mi < 4; ++mi)
#pragma unroll
    for (int ni = 0; ni < 4; ++ni)
#pragma unroll
      for (int i = 0; i < 4; ++i) {
        const int row = bm + wm + mi * 16 + l16 * 4 + i;  // C-frag: row = (lane>>4)*4 + i
        const int col = bn + wn + ni * 16 + l15;
        unsafeAtomicAdd(&sout[(size_t)row * 1024 + col], sacc[mi][ni][i]);
      }
}

extern "C" void kernel_launch(void* const* d_in, const int* in_sizes, int n_in,
                              void* d_out, int out_size, void* d_ws, size_t ws_size,
                              hipStream_t stream) {
  const float* s0 = (const float*)d_in[0];
  const float* s1 = (const float*)d_in[1];
  const float* geno = (const float*)d_in[2];
  const float* Ws = (const float*)d_in[3];
  const float* Wb = (const float*)d_in[4];
  const float* bs = (const float*)d_in[5];

  // ws layout: WsT 70M bf16 | WbT 40M bf16 | S0,S1,T0,T1,T2 4M bf16 each | S 4M f32
  unsigned short* WsT = (unsigned short*)d_ws;
  unsigned short* WbT = WsT + 70ull * 1024 * 1024;
  unsigned short* S0 = WbT + 20ull * 2048 * 1024;
  unsigned short* S1 = S0 + 4096ull * 1024;
  unsigned short* T0 = S1 + 4096ull * 1024;
  unsigned short* T1 = T0 + 4096ull * 1024;
  unsigned short* T2 = T1 + 4096ull * 1024;
  float* S = (float*)(T2 + 4096ull * 1024);

  cvt_kernel<<<4096, 256, 0, stream>>>(s0, S0);
  cvt_kernel<<<4096, 256, 0, stream>>>(s1, S1);
  zero_kernel<<<4096, 256, 0, stream>>>(S);
  zero_kernel<<<4096, 256, 0, stream>>>((float*)d_out);
  transpose_kernel<<<70 * 256, 256, 0, stream>>>(Ws, WsT, 1024);
  transpose_kernel<<<20 * 512, 256, 0, stream>>>(Wb, WbT, 2048);

  // D-input edge: one segment
  auto SS = [&](const unsigned short* x, int si, int l) {
    SegCfg c;
    c.x = x;
    c.w = WsT + (size_t)si * 5 * 1024 * 1024;
    c.wops = (size_t)1024 * 1024;
    c.l = l; c.last = 1;
    return c;
  };
  // concat(s0,s1) edge: two segments (k 0..1023 from S0, 1024..2047 from S1)
  auto BH = [&](int bi, int half, int l) {
    SegCfg c;
    c.x = half ? S1 : S0;
    c.w = WbT + (size_t)bi * 5 * 2048 * 1024 + (size_t)half * 1024 * 1024;
    c.wops = (size_t)2048 * 1024;
    c.l = l; c.last = half;
    return c;
  };

  dim3 grid(8, 32, 5);  // bn x bm x op
  {
    NodeArgs a{}; a.nseg = 4;
    a.s[0] = SS(S0, 0, 0); a.s[1] = SS(S1, 1, 1);
    a.s[2] = BH(0, 0, 2); a.s[3] = BH(0, 1, 2);
    node_gemm<<<grid, 256, 0, stream>>>(a, geno, bs, S);
    cvtzero_kernel<<<4096, 256, 0, stream>>>(S, T0);
  }
  {
    NodeArgs a{}; a.nseg = 5;
    a.s[0] = SS(S0, 2, 3); a.s[1] = SS(S1, 3, 4);
    a.s[2] = BH(1, 0, 5); a.s[3] = BH(1, 1, 5);
    a.s[4] = SS(T0, 4, 6);
    node_gemm<<<grid, 256, 0, stream>>>(a, geno, bs, S);
    cvtzero_kernel<<<4096, 256, 0, stream>>>(S, T1);
  }
  {
    NodeArgs a{}; a.nseg = 6;
    a.s[0] = SS(S0, 5, 7); a.s[1] = SS(S1, 6, 8);
    a.s[2] = BH(2, 0, 9); a.s[3] = BH(2, 1, 9);
    a.s[4] = SS(T0, 7, 10); a.s[5] = SS(T1, 8, 11);
    node_gemm<<<grid, 256, 0, stream>>>(a, geno, bs, S);
    cvtzero_kernel<<<4096, 256, 0, stream>>>(S, T2);
  }
  {
    NodeArgs a{}; a.nseg = 7;
    a.s[0] = SS(S0, 9, 12); a.s[1] = SS(S1, 10, 13);
    a.s[2] = BH(3, 0, 14); a.s[3] = BH(3, 1, 14);
    a.s[4] = SS(T0, 11, 15); a.s[5] = SS(T1, 12, 16); a.s[6] = SS(T2, 13, 17);
    node_gemm<<<grid, 256, 0, stream>>>(a, geno, bs, (float*)d_out);
  }
}

// Round 2
// 2482.800 us; speedup vs baseline: 1.1442x; 1.1381x over previous
//
#include <hip/hip_runtime.h>
#include <hip/hip_bf16.h>
#include <cstdint>
#include <cstddef>

typedef __attribute__((ext_vector_type(8))) short bf16x8;
typedef __attribute__((ext_vector_type(4))) float f32x4;

#define DEV __device__ __forceinline__

DEV unsigned short f2bf(float f) {
  unsigned int u = __float_as_uint(f);
  return (unsigned short)((u + 0x7fffu + ((u >> 16) & 1u)) >> 16);
}

DEV void gl_lds16(const unsigned short* g, unsigned short* l) {
  __builtin_amdgcn_global_load_lds(
      (__attribute__((address_space(1))) const void*)g,
      (__attribute__((address_space(3))) void*)l, 16, 0, 0);
}

// ---- states fp32 -> bf16 (exact grid: 4096 blocks x 256 thr x 1 float4) ----
__global__ __launch_bounds__(256) void cvt_kernel(const float* __restrict__ src,
                                                  unsigned short* __restrict__ dst) {
  size_t i = (size_t)blockIdx.x * 256 + threadIdx.x;
  float4 v = ((const float4*)src)[i];
  ushort4 o;
  o.x = f2bf(v.x); o.y = f2bf(v.y); o.z = f2bf(v.z); o.w = f2bf(v.w);
  ((ushort4*)dst)[i] = o;
}

// ---- zero an fp32 buffer (grid 4096 x 256 x float4 = 4M floats) ----
__global__ __launch_bounds__(256) void zero_kernel(float* __restrict__ p) {
  size_t i = (size_t)blockIdx.x * 256 + threadIdx.x;
  ((float4*)p)[i] = make_float4(0.f, 0.f, 0.f, 0.f);
}

// ---- S fp32 -> bf16 state, and re-zero S for the next node ----
__global__ __launch_bounds__(256) void cvtzero_kernel(float* __restrict__ s,
                                                      unsigned short* __restrict__ dst) {
  size_t i = (size_t)blockIdx.x * 256 + threadIdx.x;
  float4 v = ((float4*)s)[i];
  ushort4 o;
  o.x = f2bf(v.x); o.y = f2bf(v.y); o.z = f2bf(v.z); o.w = f2bf(v.w);
  ((ushort4*)dst)[i] = o;
  ((float4*)s)[i] = make_float4(0.f, 0.f, 0.f, 0.f);
}

// ---- weights: src [nmat][K][1024] f32 -> dst bf16, transposed, K-half-split:
// element (n, k) stored at mat*1024*K + (k>>10)*1024*1024 + n*1024 + (k&1023)
// => every 1024-K segment is a [1024 n][1024 k] matrix with uniform stride 1024.
__global__ __launch_bounds__(256) void transpose_kernel(const float* __restrict__ src,
                                                        unsigned short* __restrict__ dst,
                                                        int K) {
  __shared__ float tile[64][68];
  const int t = threadIdx.x;
  const int tpm = (K >> 6) * 16;  // 64x64 tiles per matrix
  const int mat = blockIdx.x / tpm;
  const int r = blockIdx.x % tpm;
  const int tk = r >> 4;
  const int tn = r & 15;
  const size_t sbase = (size_t)mat * K * 1024 + (size_t)tk * 64 * 1024 + (size_t)tn * 64;
#pragma unroll
  for (int p = 0; p < 4; ++p) {
    int row = p * 16 + (t >> 4);
    int c4 = (t & 15) * 4;
    float4 v = *(const float4*)&src[sbase + (size_t)row * 1024 + c4];
    *(float4*)&tile[row][c4] = v;
  }
  __syncthreads();
  const int kbase = tk * 64;
  const size_t dbase = (size_t)mat * 1024 * K + (size_t)(kbase >> 10) * 1024 * 1024 +
                       (size_t)tn * 64 * 1024 + (size_t)(kbase & 1023);
#pragma unroll
  for (int p = 0; p < 4; ++p) {
    int n = p * 16 + (t >> 4);
    int k4 = (t & 15) * 4;
    ushort4 o;
    o.x = f2bf(tile[k4 + 0][n]);
    o.y = f2bf(tile[k4 + 1][n]);
    o.z = f2bf(tile[k4 + 2][n]);
    o.w = f2bf(tile[k4 + 3][n]);
    *(ushort4*)&dst[dbase + (size_t)n * 1024 + k4] = o;
  }
}

// A segment is a K=1024 slice of one edge's GEMM. Concat(2D-input) edges are two
// segments sharing the accumulator; epilogue fires only where last=1.
struct SegCfg {
  const unsigned short* x;  // A rows (bf16, stride 1024)
  const unsigned short* w;  // W base for op 0 (bf16, [1024 n][1024 k], stride 1024)
  size_t wops;              // per-op stride (inlen*1024)
  int l;                    // layer index into genotype/bs
  int last;                 // 1 => run epilogue after this segment
};
struct NodeArgs {
  SegCfg s[7];
  int nseg;  // == NSEG template arg
};

// Depth-4 counted-vmcnt pipeline (T3+T4): 4 LDS buffer sets rotate; each step:
//   vmcnt(12)            -> own stage for THIS step retired (3 newer stages stay in flight)
//   s_barrier            -> all waves' stage for this buf retired
//   ds_read frags        -> compiler-tracked LDS loads
//   lgkmcnt(0)+s_barrier -> all waves done READING this buf (WAR vs restage)
//   stage(step+4)        -> 4 global_load_lds into the buf just consumed
//   16 MFMA
// No vmcnt(0) anywhere in the main loop. Raw barriers (no implicit drain).
#define PIPE_STEP(BUF, SA, SB)                                                   \
  {                                                                              \
    asm volatile("s_waitcnt vmcnt(12)" ::: "memory");                            \
    __builtin_amdgcn_s_barrier();                                                \
    __builtin_amdgcn_sched_barrier(0);                                           \
    bf16x8 af[4], bfr[4];                                                        \
    _Pragma("unroll") for (int mi = 0; mi < 4; ++mi)                             \
        af[mi] = *(const bf16x8*)&lds[(BUF) * 8192 + aof[mi]];                   \
    _Pragma("unroll") for (int ni = 0; ni < 4; ++ni)                             \
        bfr[ni] = *(const bf16x8*)&lds[(BUF) * 8192 + 4096 + bof[ni]];           \
    asm volatile("s_waitcnt lgkmcnt(0)" ::: "memory");                           \
    __builtin_amdgcn_sched_barrier(0);                                           \
    __builtin_amdgcn_s_barrier();                                                \
    __builtin_amdgcn_sched_barrier(0);                                           \
    {                                                                            \
      unsigned short* da = lds + (BUF) * 8192 + t * 8;                           \
      gl_lds16((SA), da);                                                        \
      gl_lds16((SA) + 64 * 1024, da + 2048);                                     \
      gl_lds16((SB), da + 4096);                                                 \
      gl_lds16((SB) + 64 * 1024, da + 6144);                                     \
    }                                                                            \
    _Pragma("unroll") for (int mi = 0; mi < 4; ++mi)                             \
        _Pragma("unroll") for (int ni = 0; ni < 4; ++ni)                         \
            hacc[mi][ni] = __builtin_amdgcn_mfma_f32_16x16x32_bf16(              \
                af[mi], bfr[ni], hacc[mi][ni], 0, 0, 0);                         \
  }

template <int NSEG>
__global__ __launch_bounds__(256, 2) void node_gemm(NodeArgs na,
                                                    const float* __restrict__ genotype,
                                                    const float* __restrict__ bs,
                                                    float* __restrict__ sout) {
  __shared__ unsigned short lds[32768];  // 4 bufs x (A 4096 | B 4096) shorts = 64 KB

  const int t = threadIdx.x;
  const int lane = t & 63;
  const int w = t >> 6;
  const int wm = (w & 1) * 64;
  const int wn = (w >> 1) * 64;
  const int bn = blockIdx.x * 128;
  const int bm = blockIdx.y * 128;
  const int kop = blockIdx.z;  // which of the 5 candidate ops (uniform per block)
  const int l15 = lane & 15;
  const int l16 = lane >> 4;

  // staging decode: thread t's linear LDS slot (t*16B) corresponds to
  // row = (t>>5)*8 + (t&7), chunk = (t>>3)&3 in the conflict-free block layout.
  const int srow = ((t >> 5) << 3) | (t & 7);
  const int schunk = (t >> 3) & 3;
  const size_t aoffg = (size_t)(bm + srow) * 1024 + schunk * 8;
  const size_t boffg = (size_t)(bn + srow) * 1024 + schunk * 8;

  // per-lane fragment read offsets (shorts), constant over K
  int aof[4], bof[4];
#pragma unroll
  for (int mi = 0; mi < 4; ++mi) {
    int r = wm + mi * 16 + l15;
    aof[mi] = (r >> 3) * 256 + l16 * 64 + (r & 7) * 8;
  }
#pragma unroll
  for (int ni = 0; ni < 4; ++ni) {
    int r = wn + ni * 16 + l15;
    bof[ni] = (r >> 3) * 256 + l16 * 64 + (r & 7) * 8;
  }

  // preload per-segment genotype weight + bias fragment (keeps the main loop's
  // vmcnt count pure: no global loads between pipeline steps)
  float br[NSEG][4];
  float wl[NSEG];
#pragma unroll
  for (int e = 0; e < NSEG; ++e) {
    const int l = na.s[e].l;
    wl[e] = genotype[l * 5 + kop];
#pragma unroll
    for (int ni = 0; ni < 4; ++ni)
      br[e][ni] = bs[((size_t)l * 5 + kop) * 1024 + bn + wn + ni * 16 + l15];
  }

  f32x4 sacc[4][4];
  f32x4 hacc[4][4];
#pragma unroll
  for (int mi = 0; mi < 4; ++mi)
#pragma unroll
    for (int ni = 0; ni < 4; ++ni) {
      sacc[mi][ni] = (f32x4){0.f, 0.f, 0.f, 0.f};
      hacc[mi][ni] = (f32x4){0.f, 0.f, 0.f, 0.f};
    }

  // prologue: stage steps 0..3 of segment 0 into bufs 0..3 (16 loads in flight)
  {
    const unsigned short* pa0 = na.s[0].x + aoffg;
    const unsigned short* pb0 = na.s[0].w + (size_t)kop * na.s[0].wops + boffg;
#pragma unroll
    for (int i = 0; i < 4; ++i) {
      unsigned short* da = lds + i * 8192 + t * 8;
      gl_lds16(pa0 + i * 32, da);
      gl_lds16(pa0 + i * 32 + 64 * 1024, da + 2048);
      gl_lds16(pb0 + i * 32, da + 4096);
      gl_lds16(pb0 + i * 32 + 64 * 1024, da + 6144);
    }
  }

#pragma unroll
  for (int e = 0; e < NSEG; ++e) {
    const unsigned short* pa = na.s[e].x + aoffg;
    const unsigned short* pb = na.s[e].w + (size_t)kop * na.s[e].wops + boffg;
    const int en = (e + 1 < NSEG) ? e + 1 : 0;  // last segment stages dummy (seg 0)
    const unsigned short* pna = na.s[en].x + aoffg;
    const unsigned short* pnb = na.s[en].w + (size_t)kop * na.s[en].wops + boffg;

#pragma unroll 1
    for (int m = 0; m < 8; ++m) {
      // steps 4m..4m+3 computed; steps 4m+4..4m+7 staged (tail: next segment 0..3)
      const unsigned short* spa = (m < 7) ? (pa + (size_t)(4 * m + 4) * 32) : pna;
      const unsigned short* spb = (m < 7) ? (pb + (size_t)(4 * m + 4) * 32) : pnb;
      PIPE_STEP(0, spa, spb)
      PIPE_STEP(1, spa + 32, spb + 32)
      PIPE_STEP(2, spa + 64, spb + 64)
      PIPE_STEP(3, spa + 96, spb + 96)
    }

    if (na.s[e].last) {  // uniform branch
      const float wlk = wl[e];
#pragma unroll
      for (int ni = 0; ni < 4; ++ni) {
        const float bias = br[e][ni];  // C-frag: col = lane&15
#pragma unroll
        for (int mi = 0; mi < 4; ++mi)
#pragma unroll
          for (int i = 0; i < 4; ++i) {
            float h = hacc[mi][ni][i] + bias;
            float a;
            if (kop == 0) a = h;
            else if (kop == 1) a = fmaxf(h, 0.f);
            else if (kop == 2) a = 1.f - 2.f / (__expf(2.f * h) + 1.f);  // tanh, NaN-free
            else if (kop == 3) a = 1.f / (1.f + __expf(-h));             // sigmoid
            else a = (h > 0.f) ? h : 0.2f * h;                           // leaky_relu(0.2)
            sacc[mi][ni][i] += wlk * a;
            hacc[mi][ni][i] = 0.f;
          }
      }
    }
  }

  // one atomic pass per block: 5 op-blocks reduce into sout
#pragma unroll
  for (int mi = 0; mi < 4; ++mi)
#pragma unroll
    for (int ni = 0; ni < 4; ++ni)
#pragma unroll
      for (int i = 0; i < 4; ++i) {
        const int row = bm + wm + mi * 16 + l16 * 4 + i;  // C-frag: row = (lane>>4)*4 + i
        const int col = bn + wn + ni * 16 + l15;
        unsafeAtomicAdd(&sout[(size_t)row * 1024 + col], sacc[mi][ni][i]);
      }
}

extern "C" void kernel_launch(void* const* d_in, const int* in_sizes, int n_in,
                              void* d_out, int out_size, void* d_ws, size_t ws_size,
                              hipStream_t stream) {
  const float* s0 = (const float*)d_in[0];
  const float* s1 = (const float*)d_in[1];
  const float* geno = (const float*)d_in[2];
  const float* Ws = (const float*)d_in[3];
  const float* Wb = (const float*)d_in[4];
  const float* bs = (const float*)d_in[5];

  // ws layout: WsT 70M bf16 | WbT 40M bf16 | S0,S1,T0,T1,T2 4M bf16 each | S 4M f32
  unsigned short* WsT = (unsigned short*)d_ws;
  unsigned short* WbT = WsT + 70ull * 1024 * 1024;
  unsigned short* S0 = WbT + 20ull * 2048 * 1024;
  unsigned short* S1 = S0 + 4096ull * 1024;
  unsigned short* T0 = S1 + 4096ull * 1024;
  unsigned short* T1 = T0 + 4096ull * 1024;
  unsigned short* T2 = T1 + 4096ull * 1024;
  float* S = (float*)(T2 + 4096ull * 1024);

  cvt_kernel<<<4096, 256, 0, stream>>>(s0, S0);
  cvt_kernel<<<4096, 256, 0, stream>>>(s1, S1);
  zero_kernel<<<4096, 256, 0, stream>>>(S);
  zero_kernel<<<4096, 256, 0, stream>>>((float*)d_out);
  transpose_kernel<<<70 * 256, 256, 0, stream>>>(Ws, WsT, 1024);
  transpose_kernel<<<20 * 512, 256, 0, stream>>>(Wb, WbT, 2048);

  // D-input edge: one segment
  auto SS = [&](const unsigned short* x, int si, int l) {
    SegCfg c;
    c.x = x;
    c.w = WsT + (size_t)si * 5 * 1024 * 1024;
    c.wops = (size_t)1024 * 1024;
    c.l = l; c.last = 1;
    return c;
  };
  // concat(s0,s1) edge: two segments (k 0..1023 from S0, 1024..2047 from S1)
  auto BH = [&](int bi, int half, int l) {
    SegCfg c;
    c.x = half ? S1 : S0;
    c.w = WbT + (size_t)bi * 5 * 2048 * 1024 + (size_t)half * 1024 * 1024;
    c.wops = (size_t)2048 * 1024;
    c.l = l; c.last = half;
    return c;
  };

  dim3 grid(8, 32, 5);  // bn x bm x op (default id%8 XCD mapping clusters by bn)
  {
    NodeArgs a{}; a.nseg = 4;
    a.s[0] = SS(S0, 0, 0); a.s[1] = SS(S1, 1, 1);
    a.s[2] = BH(0, 0, 2); a.s[3] = BH(0, 1, 2);
    node_gemm<4><<<grid, 256, 0, stream>>>(a, geno, bs, S);
    cvtzero_kernel<<<4096, 256, 0, stream>>>(S, T0);
  }
  {
    NodeArgs a{}; a.nseg = 5;
    a.s[0] = SS(S0, 2, 3); a.s[1] = SS(S1, 3, 4);
    a.s[2] = BH(1, 0, 5); a.s[3] = BH(1, 1, 5);
    a.s[4] = SS(T0, 4, 6);
    node_gemm<5><<<grid, 256, 0, stream>>>(a, geno, bs, S);
    cvtzero_kernel<<<4096, 256, 0, stream>>>(S, T1);
  }
  {
    NodeArgs a{}; a.nseg = 6;
    a.s[0] = SS(S0, 5, 7); a.s[1] = SS(S1, 6, 8);
    a.s[2] = BH(2, 0, 9); a.s[3] = BH(2, 1, 9);
    a.s[4] = SS(T0, 7, 10); a.s[5] = SS(T1, 8, 11);
    node_gemm<6><<<grid, 256, 0, stream>>>(a, geno, bs, S);
    cvtzero_kernel<<<4096, 256, 0, stream>>>(S, T2);
  }
  {
    NodeArgs a{}; a.nseg = 7;
    a.s[0] = SS(S0, 9, 12); a.s[1] = SS(S1, 10, 13);
    a.s[2] = BH(3, 0, 14); a.s[3] = BH(3, 1, 14);
    a.s[4] = SS(T0, 11, 15); a.s[5] = SS(T1, 12, 16); a.s[6] = SS(T2, 13, 17);
    node_gemm<7><<<grid, 256, 0, stream>>>(a, geno, bs, (float*)d_out);
  }
}